// Round 8
// baseline (1982.176 us; speedup 1.0000x reference)
//
#include <hip/hip_runtime.h>
#include <hip/hip_bf16.h>

#define BATCH 4096
#define NEXP  16
#define DIN   2048
#define DOUT  2048

#define BM 128
#define BN 128
#define NKT 32            // 32 k-tiles of 64 elements each

#define WS_X_OFF  65536
#define WS_X_BYTES ((size_t)BATCH * 4096)   // 4096 rows x 2048 bf16

typedef __attribute__((ext_vector_type(4))) float f32x4;
typedef __attribute__((ext_vector_type(8))) short bf16x8;

// --- Kernel 1: bucket sample indices by expert; write mxs/actions tail ---
__global__ void sort_kernel(const int* __restrict__ actions,
                            const float* __restrict__ mxs,
                            float* __restrict__ out_tail,
                            int* __restrict__ offs,
                            int* __restrict__ sorted) {
    __shared__ int s_cnt[NEXP];
    __shared__ int s_cur[NEXP];
    const int tid = threadIdx.x;
    if (tid < NEXP) s_cnt[tid] = 0;
    __syncthreads();
    for (int i = tid; i < BATCH; i += blockDim.x) {
        int a = actions[i];
        atomicAdd(&s_cnt[a], 1);
        out_tail[i] = mxs[i];
        out_tail[BATCH + i] = (float)a;
    }
    __syncthreads();
    if (tid == 0) {
        int run = 0;
        for (int e = 0; e < NEXP; ++e) { offs[e] = run; s_cur[e] = run; run += s_cnt[e]; }
        offs[NEXP] = run;
    }
    __syncthreads();
    // Bucket order is atomics-dependent, but each sample's output is computed
    // independently with fixed k-order -> output bit-deterministic.
    for (int i = tid; i < BATCH; i += blockDim.x) {
        int e = actions[i];
        int pos = atomicAdd(&s_cur[e], 1);
        sorted[pos] = i;
    }
}

// fp32 pair -> packed bf16 (round-to-nearest-even): [bf16(x1) | bf16(x0)]
__device__ __forceinline__ unsigned rne2(float x0, float x1) {
    unsigned b0 = __float_as_uint(x0), b1 = __float_as_uint(x1);
    b0 = b0 + 0x7FFFu + ((b0 >> 16) & 1u);
    b1 = b1 + 0x7FFFu + ((b1 >> 16) & 1u);
    return (b1 & 0xFFFF0000u) | (b0 >> 16);
}

// LDS element index: row r = 64 bf16 (128 B = 8 x 16B blocks), physical block
// = kb ^ (r&7). Under the 16-lane-phase bank model this is conflict-free for
// both our write and read patterns (r3/r7 measured ~0 conflicts).
__device__ __forceinline__ int lidx(int r, int kb) {
    return r * 64 + ((kb ^ (r & 7)) << 3);
}

// --- Kernel 1b: X -> bf16 (RNE), gathered by sorted position, pre-swizzled
// with key = EXPERT-LOCAL position & 7 (matches GEMM LDS row key; r7-verified).
__global__ void xsplit_kernel(const float* __restrict__ xs,
                              const int* __restrict__ sorted,
                              const int* __restrict__ offs,
                              const int* __restrict__ actions,
                              unsigned char* __restrict__ xws) {
    const int rm = blockIdx.x * 4 + (threadIdx.x >> 6);
    const int t = threadIdx.x & 63;
    const int c = t >> 1;          // chunk (64 bf16 = 128 B) 0..31
    const int h = t & 1;           // half: logical blocks 4h..4h+3
    const int src = sorted[rm];
    const int e = actions[src];
    const int key = (rm - offs[e]) & 7;
    const float* s = xs + (size_t)src * DIN + c * 64 + h * 32;
    uint4 blk[4];
#pragma unroll
    for (int j = 0; j < 4; ++j) {
        float4 a = *(const float4*)(s + 8 * j);
        float4 b = *(const float4*)(s + 8 * j + 4);
        blk[j].x = rne2(a.x, a.y); blk[j].y = rne2(a.z, a.w);
        blk[j].z = rne2(b.x, b.y); blk[j].w = rne2(b.z, b.w);
    }
    uint4* drow = (uint4*)(xws + (size_t)rm * 4096 + c * 128);
#pragma unroll
    for (int j = 0; j < 4; ++j)
        drow[(4 * h + j) ^ key] = blk[j];
}

// --- Kernel 2: grouped GEMM, pure bf16 (1 product). X via global_load_lds
// (dbuf, counted vmcnt); W fp32->bf16 in-reg pipeline. BK=64, 32 iters. ---
// grid = (m=32 fastest, n=16, e=16); block 256 (2x2 waves, wave tile 64x64)
__global__ __launch_bounds__(256, 3)
void gemm_kernel(const unsigned char* __restrict__ xws,
                 const float* __restrict__ W,
                 const float* __restrict__ bias,
                 const int* __restrict__ offs,
                 const int* __restrict__ sorted,
                 float* __restrict__ out) {
    __shared__ __align__(16) unsigned short Xs[2][BM * 64];  // 2 x 16 KB
    __shared__ __align__(16) unsigned short Wl[BN * 64];     // 16 KB

    const int e = blockIdx.z;
    const int start = offs[e];
    const int cnt = offs[e + 1] - start;
    const int m0 = blockIdx.x * BM;
    if (m0 >= cnt) return;
    const int n0 = blockIdx.y * BN;

    const int tid = threadIdx.x;
    const int lane = tid & 63;
    const int wave = tid >> 6;
    const int wm = wave >> 1, wn = wave & 1;
    const int g = lane >> 4, rl = lane & 15;

    // W staging role: row swr (0..127), k-half wc (0..1) -> 32 floats.
    const int swr = tid & 127;
    const int wc = tid >> 7;
    const float* wsrc = W + ((size_t)e * DOUT + n0 + swr) * DIN + wc * 32;

    // X gload sources: GLOBAL sorted row = start + m0 + local row; clamp
    // keeps OOB staging in-bounds (those rows are never written back).
    const unsigned char* xsrc_i[4];
#pragma unroll
    for (int i = 0; i < 4; ++i) {
        int rg = start + m0 + wave * 32 + 8 * i + (lane >> 3);
        if (rg > BATCH - 1) rg = BATCH - 1;
        xsrc_i[i] = xws + (size_t)rg * 4096 + (size_t)(lane & 7) * 16;
    }

#define STAGE_X(BUF, KT) do {                                                  \
    _Pragma("unroll")                                                          \
    for (int _i = 0; _i < 4; ++_i)                                             \
        __builtin_amdgcn_global_load_lds(                                      \
            (const __attribute__((address_space(1))) void*)(xsrc_i[_i] + (size_t)(KT) * 128), \
            (__attribute__((address_space(3))) void*)&Xs[BUF][(wave * 32 + 8 * _i) * 64], \
            16, 0, 0);                                                         \
} while (0)

#define CONV_PWB() do {                                                        \
    _Pragma("unroll")                                                          \
    for (int _c = 0; _c < 4; ++_c) {                                           \
        pwB[4 * _c + 0] = rne2(pwF[2 * _c].x, pwF[2 * _c].y);                  \
        pwB[4 * _c + 1] = rne2(pwF[2 * _c].z, pwF[2 * _c].w);                  \
        pwB[4 * _c + 2] = rne2(pwF[2 * _c + 1].x, pwF[2 * _c + 1].y);          \
        pwB[4 * _c + 3] = rne2(pwF[2 * _c + 1].z, pwF[2 * _c + 1].w);          \
    }                                                                          \
} while (0)

    f32x4 acc[4][4];
#pragma unroll
    for (int i = 0; i < 4; ++i)
#pragma unroll
        for (int j = 0; j < 4; ++j) acc[i][j] = (f32x4){0.f, 0.f, 0.f, 0.f};

    // ---- prologue ----
    float4 pwF[8];
    unsigned pwB[16];
#pragma unroll
    for (int j = 0; j < 8; ++j) pwF[j] = *(const float4*)(wsrc + 4 * j);
    CONV_PWB();                              // W(0) -> pwB
#pragma unroll
    for (int j = 0; j < 8; ++j) pwF[j] = *(const float4*)(wsrc + 64 + 4 * j);  // W(1)
    STAGE_X(0, 0);

    int kt = 0;

#define KSTEP(CUR, NXT) do {                                                   \
    { /* A: ds_write W(kt) bf16 tile */                                        \
      _Pragma("unroll")                                                        \
      for (int _c = 0; _c < 4; ++_c)                                           \
          *(uint4*)&Wl[lidx(swr, wc * 4 + _c)] =                               \
              make_uint4(pwB[4 * _c], pwB[4 * _c + 1],                         \
                         pwB[4 * _c + 2], pwB[4 * _c + 3]); }                  \
    /* B: stage X(kt+1) into NXT (4 gload_lds) */                              \
    STAGE_X(NXT, (kt + 1) & (NKT - 1));                                        \
    __builtin_amdgcn_sched_barrier(0);                                         \
    { /* C: convert W(kt+1) (implicit wait retires X(kt) too); load W(kt+2) */ \
      CONV_PWB();                                                              \
      int _k2 = (kt + 2) & (NKT - 1);                                          \
      _Pragma("unroll")                                                        \
      for (int j = 0; j < 8; ++j)                                              \
          pwF[j] = *(const float4*)(wsrc + _k2 * 64 + 4 * j); }                \
    /* D: X(kt) landed, W ds_writes visible; 12 vm-ops stay in flight */       \
    __builtin_amdgcn_sched_barrier(0);                                         \
    asm volatile("s_waitcnt vmcnt(12) lgkmcnt(0)" ::: "memory");               \
    __builtin_amdgcn_sched_barrier(0);                                         \
    __builtin_amdgcn_s_barrier();                                              \
    { /* E+G: frags + 32 MFMA (compiler schedules lgkmcnt) */                  \
      __builtin_amdgcn_s_setprio(1);                                           \
      _Pragma("unroll")                                                        \
      for (int ks = 0; ks < 2; ++ks) {                                         \
          bf16x8 ah[4], bh[4];                                                 \
          _Pragma("unroll")                                                    \
          for (int mi = 0; mi < 4; ++mi)                                       \
              ah[mi] = *(const bf16x8*)&Xs[CUR][lidx(wm * 64 + mi * 16 + rl, ks * 4 + g)]; \
          _Pragma("unroll")                                                    \
          for (int ni = 0; ni < 4; ++ni)                                       \
              bh[ni] = *(const bf16x8*)&Wl[lidx(wn * 64 + ni * 16 + rl, ks * 4 + g)]; \
          _Pragma("unroll")                                                    \
          for (int mi = 0; mi < 4; ++mi)                                       \
              _Pragma("unroll")                                                \
              for (int ni = 0; ni < 4; ++ni)                                   \
                  acc[mi][ni] = __builtin_amdgcn_mfma_f32_16x16x32_bf16(ah[mi], bh[ni], acc[mi][ni], 0, 0, 0); \
      }                                                                        \
      __builtin_amdgcn_s_setprio(0); }                                         \
    /* F: all LDS reads retired (MFMA dep) -> next A safe after barrier */     \
    __builtin_amdgcn_sched_barrier(0);                                         \
    asm volatile("s_waitcnt lgkmcnt(0)" ::: "memory");                         \
    __builtin_amdgcn_sched_barrier(0);                                         \
    __builtin_amdgcn_s_barrier();                                              \
    ++kt;                                                                      \
} while (0)

#pragma unroll 1
    for (int it = 0; it < NKT / 2; ++it) {
        KSTEP(0, 1);
        KSTEP(1, 0);
    }
#undef KSTEP
#undef STAGE_X
#undef CONV_PWB

    // ---- epilogue: bias add + scatter rows (mapping verified r3..r7) ----
    float bv[4];
#pragma unroll
    for (int ni = 0; ni < 4; ++ni)
        bv[ni] = bias[(size_t)e * DOUT + n0 + wn * 64 + ni * 16 + rl];
#pragma unroll
    for (int mi = 0; mi < 4; ++mi) {
#pragma unroll
        for (int j = 0; j < 4; ++j) {
            int rm = m0 + wm * 64 + mi * 16 + g * 4 + j;
            if (rm < cnt) {
                int s = sorted[start + rm];
                float* orow = out + (size_t)s * DOUT + n0 + wn * 64 + rl;
#pragma unroll
                for (int ni = 0; ni < 4; ++ni)
                    orow[ni * 16] = acc[mi][ni][j] + bv[ni];
            }
        }
    }
}

// --- Fallback (round-5 proven 3-product kernel) if workspace too small ---
__device__ __forceinline__ void split_pair(float x0, float x1, unsigned& h, unsigned& l) {
    unsigned b0 = __float_as_uint(x0), b1 = __float_as_uint(x1);
    unsigned h0 = b0 & 0xFFFF0000u;
    unsigned h1 = b1 & 0xFFFF0000u;
    h = h1 | (b0 >> 16);
    unsigned l0 = __float_as_uint(x0 - __uint_as_float(h0));
    unsigned l1 = __float_as_uint(x1 - __uint_as_float(h1));
    l = (l1 & 0xFFFF0000u) | (l0 >> 16);
}
__device__ __forceinline__ void split_f4pair(float4 a, float4 b, uint4& h, uint4& l) {
    split_pair(a.x, a.y, h.x, l.x);
    split_pair(a.z, a.w, h.y, l.y);
    split_pair(b.x, b.y, h.z, l.z);
    split_pair(b.z, b.w, h.w, l.w);
}

__global__ __launch_bounds__(256, 3)
void gemm_fb(const float* __restrict__ xs,
             const float* __restrict__ W,
             const float* __restrict__ bias,
             const int* __restrict__ offs,
             const int* __restrict__ sorted,
             float* __restrict__ out) {
    __shared__ __align__(16) unsigned short Xs[128 * 64];
    __shared__ __align__(16) unsigned short Ws[64 * 64];

    const int e = blockIdx.y;
    const int start = offs[e];
    const int cnt = offs[e + 1] - start;
    const int m0 = blockIdx.z * 128;
    if (m0 >= cnt) return;
    const int n0 = blockIdx.x * 64;

    const int tid = threadIdx.x;
    const int lane = tid & 63;
    const int wave = tid >> 6;
    const int wm = wave >> 1, wn = wave & 1;
    const int srow = tid & 127, kq = tid >> 7;
    const int swr = tid >> 2, wkq = tid & 3;

    const int rm_s = m0 + srow;
    const int xrow = (rm_s < cnt) ? sorted[start + rm_s] : -1;
    const float* xsrc = xs + (size_t)(xrow < 0 ? 0 : xrow) * DIN + kq * 16;
    const float* wsrc = W + ((size_t)e * DOUT + n0 + swr) * DIN + wkq * 8;

    f32x4 acc[4][2];
#pragma unroll
    for (int i = 0; i < 4; ++i)
#pragma unroll
        for (int j = 0; j < 2; ++j) acc[i][j] = (f32x4){0.f, 0.f, 0.f, 0.f};

    float4 px[4], pw[2];
#pragma unroll
    for (int j = 0; j < 4; ++j)
        px[j] = (xrow >= 0) ? *(const float4*)(xsrc + j * 4) : make_float4(0.f, 0.f, 0.f, 0.f);
    pw[0] = *(const float4*)(wsrc);
    pw[1] = *(const float4*)(wsrc + 4);

    for (int k0 = 0; k0 < DIN; k0 += 32) {
        {
            uint4 xh0, xl0, xh1, xl1, wh, wl;
            split_f4pair(px[0], px[1], xh0, xl0);
            split_f4pair(px[2], px[3], xh1, xl1);
            split_f4pair(pw[0], pw[1], wh, wl);
            *(uint4*)&Xs[lidx(srow, 2 * kq)]         = xh0;
            *(uint4*)&Xs[lidx(srow, 2 * kq + 1)]     = xh1;
            *(uint4*)&Xs[lidx(srow, 4 + 2 * kq)]     = xl0;
            *(uint4*)&Xs[lidx(srow, 4 + 2 * kq + 1)] = xl1;
            *(uint4*)&Ws[lidx(swr, wkq)]             = wh;
            *(uint4*)&Ws[lidx(swr, 4 + wkq)]         = wl;
        }
        __syncthreads();
        {
            int kn = (k0 + 32 < DIN) ? (k0 + 32) : 0;
#pragma unroll
            for (int j = 0; j < 4; ++j)
                px[j] = (xrow >= 0) ? *(const float4*)(xsrc + kn + j * 4) : make_float4(0.f, 0.f, 0.f, 0.f);
            pw[0] = *(const float4*)(wsrc + kn);
            pw[1] = *(const float4*)(wsrc + kn + 4);
        }
        {
            const int g = lane >> 4, rl = lane & 15;
            bf16x8 ah[4], al[4], bh[2], bl[2];
#pragma unroll
            for (int mi = 0; mi < 4; ++mi) {
                int R = wm * 64 + mi * 16 + rl;
                ah[mi] = *(const bf16x8*)&Xs[lidx(R, g)];
                al[mi] = *(const bf16x8*)&Xs[lidx(R, 4 + g)];
            }
#pragma unroll
            for (int ni = 0; ni < 2; ++ni) {
                int R = wn * 32 + ni * 16 + rl;
                bh[ni] = *(const bf16x8*)&Ws[lidx(R, g)];
                bl[ni] = *(const bf16x8*)&Ws[lidx(R, 4 + g)];
            }
#pragma unroll
            for (int mi = 0; mi < 4; ++mi)
#pragma unroll
                for (int ni = 0; ni < 2; ++ni)
                    acc[mi][ni] = __builtin_amdgcn_mfma_f32_16x16x32_bf16(ah[mi], bh[ni], acc[mi][ni], 0, 0, 0);
#pragma unroll
            for (int mi = 0; mi < 4; ++mi)
#pragma unroll
                for (int ni = 0; ni < 2; ++ni)
                    acc[mi][ni] = __builtin_amdgcn_mfma_f32_16x16x32_bf16(ah[mi], bl[ni], acc[mi][ni], 0, 0, 0);
#pragma unroll
            for (int mi = 0; mi < 4; ++mi)
#pragma unroll
                for (int ni = 0; ni < 2; ++ni)
                    acc[mi][ni] = __builtin_amdgcn_mfma_f32_16x16x32_bf16(al[mi], bh[ni], acc[mi][ni], 0, 0, 0);
        }
        __syncthreads();
    }

    const int g = lane >> 4, rl = lane & 15;
    float bv[2];
#pragma unroll
    for (int ni = 0; ni < 2; ++ni)
        bv[ni] = bias[(size_t)e * DOUT + n0 + wn * 32 + ni * 16 + rl];
#pragma unroll
    for (int mi = 0; mi < 4; ++mi) {
#pragma unroll
        for (int j = 0; j < 4; ++j) {
            int rm = m0 + wm * 64 + mi * 16 + g * 4 + j;
            if (rm < cnt) {
                int s = sorted[start + rm];
                float* orow = out + (size_t)s * DOUT + n0 + wn * 32 + rl;
#pragma unroll
                for (int ni = 0; ni < 2; ++ni)
                    orow[ni * 16] = acc[mi][ni][j] + bv[ni];
            }
        }
    }
}

extern "C" void kernel_launch(void* const* d_in, const int* in_sizes, int n_in,
                              void* d_out, int out_size, void* d_ws, size_t ws_size,
                              hipStream_t stream) {
    const float* xs      = (const float*)d_in[0];
    const float* mxs     = (const float*)d_in[1];
    const int*   actions = (const int*)d_in[2];
    const float* W       = (const float*)d_in[3];
    const float* b       = (const float*)d_in[4];
    float* out = (float*)d_out;

    int* ws_i   = (int*)d_ws;
    int* offs   = ws_i;         // NEXP+1
    int* sorted = ws_i + 32;    // BATCH

    sort_kernel<<<1, 1024, 0, stream>>>(actions, mxs,
                                        out + (size_t)BATCH * DOUT, offs, sorted);

    if (ws_size >= WS_X_OFF + WS_X_BYTES) {
        unsigned char* xws = (unsigned char*)d_ws + WS_X_OFF;
        xsplit_kernel<<<BATCH / 4, 256, 0, stream>>>(xs, sorted, offs, actions, xws);
        dim3 grid(BATCH / BM, DOUT / BN, NEXP);   // m fastest -> W L3 reuse
        gemm_kernel<<<grid, 256, 0, stream>>>(xws, W, b, offs, sorted, out);
    } else {
        dim3 grid(DOUT / 64, NEXP, BATCH / 128);
        gemm_fb<<<grid, 256, 0, stream>>>(xs, W, b, offs, sorted, out);
    }
}

// Round 9
// 196.603 us; speedup vs baseline: 10.0821x; 10.0821x over previous
//
#include <hip/hip_runtime.h>
#include <hip/hip_bf16.h>

#define BATCH 4096
#define NEXP  16
#define DIN   2048
#define DOUT  2048

#define BM 128
#define BN 128
#define NKT 64            // 64 k-tiles of 32 elements

#define WS_X_OFF  65536
#define WS_X_BYTES ((size_t)BATCH * 4096)   // 4096 rows x 2048 bf16

typedef __attribute__((ext_vector_type(4))) float f32x4;
typedef __attribute__((ext_vector_type(8))) short bf16x8;

// --- Kernel 1: bucket sample indices by expert; write mxs/actions tail ---
__global__ void sort_kernel(const int* __restrict__ actions,
                            const float* __restrict__ mxs,
                            float* __restrict__ out_tail,
                            int* __restrict__ offs,
                            int* __restrict__ sorted) {
    __shared__ int s_cnt[NEXP];
    __shared__ int s_cur[NEXP];
    const int tid = threadIdx.x;
    if (tid < NEXP) s_cnt[tid] = 0;
    __syncthreads();
    for (int i = tid; i < BATCH; i += blockDim.x) {
        int a = actions[i];
        atomicAdd(&s_cnt[a], 1);
        out_tail[i] = mxs[i];
        out_tail[BATCH + i] = (float)a;
    }
    __syncthreads();
    if (tid == 0) {
        int run = 0;
        for (int e = 0; e < NEXP; ++e) { offs[e] = run; s_cur[e] = run; run += s_cnt[e]; }
        offs[NEXP] = run;
    }
    __syncthreads();
    // Bucket order is atomics-dependent, but each sample's output is computed
    // independently with fixed k-order -> output bit-deterministic.
    for (int i = tid; i < BATCH; i += blockDim.x) {
        int e = actions[i];
        int pos = atomicAdd(&s_cur[e], 1);
        sorted[pos] = i;
    }
}

// fp32 pair -> packed bf16 (round-to-nearest-even): [bf16(x1) | bf16(x0)]
__device__ __forceinline__ unsigned rne2(float x0, float x1) {
    unsigned b0 = __float_as_uint(x0), b1 = __float_as_uint(x1);
    b0 = b0 + 0x7FFFu + ((b0 >> 16) & 1u);
    b1 = b1 + 0x7FFFu + ((b1 >> 16) & 1u);
    return (b1 & 0xFFFF0000u) | (b0 >> 16);
}

// ---- BK=32 tile layout: row = 32 bf16 = 64 B = 4 x 16B blocks ----
// Swizzle key f(r) = (r>>1)&3. Read (16 rows x block g): bank-slot
// (4r + g^f(r)) % 8 -> exact 2-way (free). Write: even 8-way spread = minimal.
__device__ __forceinline__ int lidx32(int r, int kb) {
    return r * 32 + ((kb ^ ((r >> 1) & 3)) << 3);
}

// Old 128B-row layout (fallback kernel only; r3/r5/r7 measured ~0 conflicts)
__device__ __forceinline__ int lidx(int r, int kb) {
    return r * 64 + ((kb ^ (r & 7)) << 3);
}

// --- Kernel 1b: X -> bf16 (RNE), gathered by sorted position, pre-swizzled.
// xws row rm: 64 k-tiles x 64B; physical block b of tile kt holds logical
// block b ^ f(local) so the GEMM's linear global_load_lds + swizzled
// ds_read recover it (both-sides involution, rule #21).
__global__ void xsplit_kernel(const float* __restrict__ xs,
                              const int* __restrict__ sorted,
                              const int* __restrict__ offs,
                              const int* __restrict__ actions,
                              unsigned char* __restrict__ xws) {
    const int rm = blockIdx.x * 4 + (threadIdx.x >> 6);
    const int t = threadIdx.x & 63;         // k-tile index 0..63
    const int src = sorted[rm];
    const int e = actions[src];
    const int f = ((rm - offs[e]) >> 1) & 3;
    const float* s = xs + (size_t)src * DIN + t * 32;
    uint4 L[4];
#pragma unroll
    for (int j = 0; j < 4; ++j) {
        float4 a = *(const float4*)(s + 8 * j);
        float4 b = *(const float4*)(s + 8 * j + 4);
        L[j].x = rne2(a.x, a.y); L[j].y = rne2(a.z, a.w);
        L[j].z = rne2(b.x, b.y); L[j].w = rne2(b.z, b.w);
    }
    uint4* dst = (uint4*)(xws + (size_t)rm * 4096 + (size_t)t * 64);
#pragma unroll
    for (int b = 0; b < 4; ++b)
        dst[b] = L[b ^ f];
}

// --- Kernel 2: grouped GEMM, pure bf16. r7's proven schedule, BK=32,
// LDS 24KB -> 5-6 blocks/CU. X via global_load_lds dbuf; W fp32->bf16
// with 2-deep pwA/pwB register pipeline (r7 sizes: 16 regs each). ---
// grid = (n=16 fastest, e=16, m=32); block 256 (2x2 waves, 64x64/wave)
__global__ __launch_bounds__(256, 3)
void gemm_kernel(const unsigned char* __restrict__ xws,
                 const float* __restrict__ W,
                 const float* __restrict__ bias,
                 const int* __restrict__ offs,
                 const int* __restrict__ sorted,
                 float* __restrict__ out) {
    __shared__ __align__(16) unsigned short Xs[2][BM * 32];  // 2 x 8 KB
    __shared__ __align__(16) unsigned short Wl[BN * 32];     // 8 KB

    const int e = blockIdx.y;
    const int start = offs[e];
    const int cnt = offs[e + 1] - start;
    const int m0 = blockIdx.z * BM;
    if (m0 >= cnt) return;
    const int n0 = blockIdx.x * BN;

    const int tid = threadIdx.x;
    const int lane = tid & 63;
    const int wave = tid >> 6;
    const int wm = wave >> 1, wn = wave & 1;
    const int g = lane >> 4, rl = lane & 15;

    // W staging role: row swr (0..127), 16-float half wc (0..1).
    const int swr = tid & 127;
    const int wc = tid >> 7;
    const float* wsrc = W + ((size_t)e * DOUT + n0 + swr) * DIN + wc * 16;

    // X gload sources (2 insts/wave, 16 rows each; lane -> row wave*32+i*16
    // + (lane>>2), 16B block lane&3). Clamp keeps OOB rows in-bounds.
    const unsigned char* xsrc_i[2];
#pragma unroll
    for (int i = 0; i < 2; ++i) {
        int rg = start + m0 + wave * 32 + i * 16 + (lane >> 2);
        if (rg > BATCH - 1) rg = BATCH - 1;
        xsrc_i[i] = xws + (size_t)rg * 4096 + (size_t)(lane & 3) * 16;
    }

#define STAGE_X(BUF, KT) do {                                                  \
    _Pragma("unroll")                                                          \
    for (int _i = 0; _i < 2; ++_i)                                             \
        __builtin_amdgcn_global_load_lds(                                      \
            (const __attribute__((address_space(1))) void*)(xsrc_i[_i] + (size_t)(KT) * 64), \
            (__attribute__((address_space(3))) void*)&Xs[BUF][(wave * 32 + _i * 16) * 32], \
            16, 0, 0);                                                         \
} while (0)

    f32x4 acc[4][4];
#pragma unroll
    for (int i = 0; i < 4; ++i)
#pragma unroll
        for (int j = 0; j < 4; ++j) acc[i][j] = (f32x4){0.f, 0.f, 0.f, 0.f};

    // ---- prologue: W(0)->pwA, W(1)->pwB, X(0) in flight ----
    float4 pwA[4], pwB[4];
#pragma unroll
    for (int j = 0; j < 4; ++j) pwA[j] = *(const float4*)(wsrc + 0 * 32 + 4 * j);
#pragma unroll
    for (int j = 0; j < 4; ++j) pwB[j] = *(const float4*)(wsrc + 1 * 32 + 4 * j);
    STAGE_X(0, 0);

    int kt = 0;

#define KSTEP(PW, CUR, NXT) do {                                               \
    { /* A: convert W(kt) (loaded 2 iters ago) + 2 ds_writes */                \
      uint4 u0, u1;                                                            \
      u0.x = rne2(PW[0].x, PW[0].y); u0.y = rne2(PW[0].z, PW[0].w);            \
      u0.z = rne2(PW[1].x, PW[1].y); u0.w = rne2(PW[1].z, PW[1].w);            \
      u1.x = rne2(PW[2].x, PW[2].y); u1.y = rne2(PW[2].z, PW[2].w);            \
      u1.z = rne2(PW[3].x, PW[3].y); u1.w = rne2(PW[3].z, PW[3].w);            \
      *(uint4*)&Wl[lidx32(swr, 2 * wc)]     = u0;                              \
      *(uint4*)&Wl[lidx32(swr, 2 * wc + 1)] = u1; }                            \
    /* B: stage X(kt+1) into NXT (2 gload_lds) */                              \
    STAGE_X(NXT, (kt + 1) & (NKT - 1));                                        \
    { /* C: W(kt+2) loads into PW (consumed 2 iters later) */                  \
      int _k2 = (kt + 2) & (NKT - 1);                                          \
      _Pragma("unroll")                                                        \
      for (int j = 0; j < 4; ++j)                                              \
          PW[j] = *(const float4*)(wsrc + _k2 * 32 + 4 * j); }                 \
    /* D: X(kt) landed (oldest 2 of 12 vm-ops) + W ds_writes visible */        \
    __builtin_amdgcn_sched_barrier(0);                                         \
    asm volatile("s_waitcnt vmcnt(10) lgkmcnt(0)" ::: "memory");               \
    __builtin_amdgcn_sched_barrier(0);                                         \
    __builtin_amdgcn_s_barrier();                                              \
    { /* E: fragment ds_reads */                                               \
      bf16x8 ah[4], bh[4];                                                     \
      _Pragma("unroll")                                                        \
      for (int mi = 0; mi < 4; ++mi)                                           \
          ah[mi] = *(const bf16x8*)&Xs[CUR][lidx32(wm * 64 + mi * 16 + rl, g)];\
      _Pragma("unroll")                                                        \
      for (int ni = 0; ni < 4; ++ni)                                           \
          bh[ni] = *(const bf16x8*)&Wl[lidx32(wn * 64 + ni * 16 + rl, g)];     \
      /* F: reads retired -> next ds_write safe after barrier */               \
      __builtin_amdgcn_sched_barrier(0);                                       \
      asm volatile("s_waitcnt lgkmcnt(0)" ::: "memory");                       \
      __builtin_amdgcn_sched_barrier(0);                                       \
      __builtin_amdgcn_s_barrier();                                            \
      /* G: 16 MFMA */                                                         \
      __builtin_amdgcn_s_setprio(1);                                           \
      _Pragma("unroll")                                                        \
      for (int mi = 0; mi < 4; ++mi)                                           \
          _Pragma("unroll")                                                    \
          for (int ni = 0; ni < 4; ++ni)                                       \
              acc[mi][ni] = __builtin_amdgcn_mfma_f32_16x16x32_bf16(ah[mi], bh[ni], acc[mi][ni], 0, 0, 0); \
      __builtin_amdgcn_s_setprio(0); }                                         \
    ++kt;                                                                      \
} while (0)

#pragma unroll 1
    for (int it = 0; it < NKT / 2; ++it) {
        KSTEP(pwA, 0, 1);
        KSTEP(pwB, 1, 0);
    }
#undef KSTEP
#undef STAGE_X

    // ---- epilogue: bias add + scatter rows (mapping verified r3..r8) ----
    float bv[4];
#pragma unroll
    for (int ni = 0; ni < 4; ++ni)
        bv[ni] = bias[(size_t)e * DOUT + n0 + wn * 64 + ni * 16 + rl];
#pragma unroll
    for (int mi = 0; mi < 4; ++mi) {
#pragma unroll
        for (int j = 0; j < 4; ++j) {
            int rm = m0 + wm * 64 + mi * 16 + g * 4 + j;
            if (rm < cnt) {
                int s = sorted[start + rm];
                float* orow = out + (size_t)s * DOUT + n0 + wn * 64 + rl;
#pragma unroll
                for (int ni = 0; ni < 4; ++ni)
                    orow[ni * 16] = acc[mi][ni][j] + bv[ni];
            }
        }
    }
}

// --- Fallback (round-5 proven 3-product kernel) if workspace too small ---
__device__ __forceinline__ void split_pair(float x0, float x1, unsigned& h, unsigned& l) {
    unsigned b0 = __float_as_uint(x0), b1 = __float_as_uint(x1);
    unsigned h0 = b0 & 0xFFFF0000u;
    unsigned h1 = b1 & 0xFFFF0000u;
    h = h1 | (b0 >> 16);
    unsigned l0 = __float_as_uint(x0 - __uint_as_float(h0));
    unsigned l1 = __float_as_uint(x1 - __uint_as_float(h1));
    l = (l1 & 0xFFFF0000u) | (l0 >> 16);
}
__device__ __forceinline__ void split_f4pair(float4 a, float4 b, uint4& h, uint4& l) {
    split_pair(a.x, a.y, h.x, l.x);
    split_pair(a.z, a.w, h.y, l.y);
    split_pair(b.x, b.y, h.z, l.z);
    split_pair(b.z, b.w, h.w, l.w);
}

__global__ __launch_bounds__(256, 3)
void gemm_fb(const float* __restrict__ xs,
             const float* __restrict__ W,
             const float* __restrict__ bias,
             const int* __restrict__ offs,
             const int* __restrict__ sorted,
             float* __restrict__ out) {
    __shared__ __align__(16) unsigned short Xs[128 * 64];
    __shared__ __align__(16) unsigned short Ws[64 * 64];

    const int e = blockIdx.y;
    const int start = offs[e];
    const int cnt = offs[e + 1] - start;
    const int m0 = blockIdx.z * 128;
    if (m0 >= cnt) return;
    const int n0 = blockIdx.x * 64;

    const int tid = threadIdx.x;
    const int lane = tid & 63;
    const int wave = tid >> 6;
    const int wm = wave >> 1, wn = wave & 1;
    const int srow = tid & 127, kq = tid >> 7;
    const int swr = tid >> 2, wkq = tid & 3;

    const int rm_s = m0 + srow;
    const int xrow = (rm_s < cnt) ? sorted[start + rm_s] : -1;
    const float* xsrc = xs + (size_t)(xrow < 0 ? 0 : xrow) * DIN + kq * 16;
    const float* wsrc = W + ((size_t)e * DOUT + n0 + swr) * DIN + wkq * 8;

    f32x4 acc[4][2];
#pragma unroll
    for (int i = 0; i < 4; ++i)
#pragma unroll
        for (int j = 0; j < 2; ++j) acc[i][j] = (f32x4){0.f, 0.f, 0.f, 0.f};

    float4 px[4], pw[2];
#pragma unroll
    for (int j = 0; j < 4; ++j)
        px[j] = (xrow >= 0) ? *(const float4*)(xsrc + j * 4) : make_float4(0.f, 0.f, 0.f, 0.f);
    pw[0] = *(const float4*)(wsrc);
    pw[1] = *(const float4*)(wsrc + 4);

    for (int k0 = 0; k0 < DIN; k0 += 32) {
        {
            uint4 xh0, xl0, xh1, xl1, wh, wl;
            split_f4pair(px[0], px[1], xh0, xl0);
            split_f4pair(px[2], px[3], xh1, xl1);
            split_f4pair(pw[0], pw[1], wh, wl);
            *(uint4*)&Xs[lidx(srow, 2 * kq)]         = xh0;
            *(uint4*)&Xs[lidx(srow, 2 * kq + 1)]     = xh1;
            *(uint4*)&Xs[lidx(srow, 4 + 2 * kq)]     = xl0;
            *(uint4*)&Xs[lidx(srow, 4 + 2 * kq + 1)] = xl1;
            *(uint4*)&Ws[lidx(swr, wkq)]             = wh;
            *(uint4*)&Ws[lidx(swr, 4 + wkq)]         = wl;
        }
        __syncthreads();
        {
            int kn = (k0 + 32 < DIN) ? (k0 + 32) : 0;
#pragma unroll
            for (int j = 0; j < 4; ++j)
                px[j] = (xrow >= 0) ? *(const float4*)(xsrc + kn + j * 4) : make_float4(0.f, 0.f, 0.f, 0.f);
            pw[0] = *(const float4*)(wsrc + kn);
            pw[1] = *(const float4*)(wsrc + kn + 4);
        }
        {
            const int gg = lane >> 4, rrl = lane & 15;
            bf16x8 ah[4], al[4], bh[2], bl[2];
#pragma unroll
            for (int mi = 0; mi < 4; ++mi) {
                int R = wm * 64 + mi * 16 + rrl;
                ah[mi] = *(const bf16x8*)&Xs[lidx(R, gg)];
                al[mi] = *(const bf16x8*)&Xs[lidx(R, 4 + gg)];
            }
#pragma unroll
            for (int ni = 0; ni < 2; ++ni) {
                int R = wn * 32 + ni * 16 + rrl;
                bh[ni] = *(const bf16x8*)&Ws[lidx(R, gg)];
                bl[ni] = *(const bf16x8*)&Ws[lidx(R, 4 + gg)];
            }
#pragma unroll
            for (int mi = 0; mi < 4; ++mi)
#pragma unroll
                for (int ni = 0; ni < 2; ++ni)
                    acc[mi][ni] = __builtin_amdgcn_mfma_f32_16x16x32_bf16(ah[mi], bh[ni], acc[mi][ni], 0, 0, 0);
#pragma unroll
            for (int mi = 0; mi < 4; ++mi)
#pragma unroll
                for (int ni = 0; ni < 2; ++ni)
                    acc[mi][ni] = __builtin_amdgcn_mfma_f32_16x16x32_bf16(ah[mi], bl[ni], acc[mi][ni], 0, 0, 0);
#pragma unroll
            for (int mi = 0; mi < 4; ++mi)
#pragma unroll
                for (int ni = 0; ni < 2; ++ni)
                    acc[mi][ni] = __builtin_amdgcn_mfma_f32_16x16x32_bf16(al[mi], bh[ni], acc[mi][ni], 0, 0, 0);
        }
        __syncthreads();
    }

    const int gg = lane >> 4, rrl = lane & 15;
    float bv[2];
#pragma unroll
    for (int ni = 0; ni < 2; ++ni)
        bv[ni] = bias[(size_t)e * DOUT + n0 + wn * 32 + ni * 16 + rrl];
#pragma unroll
    for (int mi = 0; mi < 4; ++mi) {
#pragma unroll
        for (int j = 0; j < 4; ++j) {
            int rm = m0 + wm * 64 + mi * 16 + gg * 4 + j;
            if (rm < cnt) {
                int s = sorted[start + rm];
                float* orow = out + (size_t)s * DOUT + n0 + wn * 32 + rrl;
#pragma unroll
                for (int ni = 0; ni < 2; ++ni)
                    orow[ni * 16] = acc[mi][ni][j] + bv[ni];
            }
        }
    }
}

extern "C" void kernel_launch(void* const* d_in, const int* in_sizes, int n_in,
                              void* d_out, int out_size, void* d_ws, size_t ws_size,
                              hipStream_t stream) {
    const float* xs      = (const float*)d_in[0];
    const float* mxs     = (const float*)d_in[1];
    const int*   actions = (const int*)d_in[2];
    const float* W       = (const float*)d_in[3];
    const float* b       = (const float*)d_in[4];
    float* out = (float*)d_out;

    int* ws_i   = (int*)d_ws;
    int* offs   = ws_i;         // NEXP+1
    int* sorted = ws_i + 32;    // BATCH

    sort_kernel<<<1, 1024, 0, stream>>>(actions, mxs,
                                        out + (size_t)BATCH * DOUT, offs, sorted);

    if (ws_size >= WS_X_OFF + WS_X_BYTES) {
        unsigned char* xws = (unsigned char*)d_ws + WS_X_OFF;
        xsplit_kernel<<<BATCH / 4, 256, 0, stream>>>(xs, sorted, offs, actions, xws);
        dim3 grid(DOUT / BN, NEXP, BATCH / BM);   // n fastest: dense active prefix
        gemm_kernel<<<grid, 256, 0, stream>>>(xws, W, b, offs, sorted, out);
    } else {
        dim3 grid(DOUT / 64, NEXP, BATCH / 128);
        gemm_fb<<<grid, 256, 0, stream>>>(xs, W, b, offs, sorted, out);
    }
}

// Round 10
// 171.632 us; speedup vs baseline: 11.5490x; 1.1455x over previous
//
#include <hip/hip_runtime.h>
#include <hip/hip_bf16.h>

#define BATCH 4096
#define NEXP  16
#define DIN   2048
#define DOUT  2048

#define BM 128
#define BN 64
#define NKT 64            // 64 k-tiles of 32 elements

#define WS_X_OFF  65536
#define WS_X_BYTES ((size_t)BATCH * 4096)   // 4096 rows x 2048 bf16

typedef __attribute__((ext_vector_type(4))) float f32x4;
typedef __attribute__((ext_vector_type(8))) short bf16x8;

// --- Kernel 1: bucket sample indices by expert; write mxs/actions tail ---
__global__ void sort_kernel(const int* __restrict__ actions,
                            const float* __restrict__ mxs,
                            float* __restrict__ out_tail,
                            int* __restrict__ offs,
                            int* __restrict__ sorted) {
    __shared__ int s_cnt[NEXP];
    __shared__ int s_cur[NEXP];
    const int tid = threadIdx.x;
    if (tid < NEXP) s_cnt[tid] = 0;
    __syncthreads();
    for (int i = tid; i < BATCH; i += blockDim.x) {
        int a = actions[i];
        atomicAdd(&s_cnt[a], 1);
        out_tail[i] = mxs[i];
        out_tail[BATCH + i] = (float)a;
    }
    __syncthreads();
    if (tid == 0) {
        int run = 0;
        for (int e = 0; e < NEXP; ++e) { offs[e] = run; s_cur[e] = run; run += s_cnt[e]; }
        offs[NEXP] = run;
    }
    __syncthreads();
    // Bucket order is atomics-dependent, but each sample's output is computed
    // independently with fixed k-order -> output bit-deterministic.
    for (int i = tid; i < BATCH; i += blockDim.x) {
        int e = actions[i];
        int pos = atomicAdd(&s_cur[e], 1);
        sorted[pos] = i;
    }
}

// fp32 pair -> packed bf16 (round-to-nearest-even): [bf16(x1) | bf16(x0)]
__device__ __forceinline__ unsigned rne2(float x0, float x1) {
    unsigned b0 = __float_as_uint(x0), b1 = __float_as_uint(x1);
    b0 = b0 + 0x7FFFu + ((b0 >> 16) & 1u);
    b1 = b1 + 0x7FFFu + ((b1 >> 16) & 1u);
    return (b1 & 0xFFFF0000u) | (b0 >> 16);
}

// ---- BK=32 tile layout: row = 32 bf16 = 64 B = 4 x 16B blocks ----
// Swizzle key f(r) = (r>>1)&3. Verified conflict-free in r9 (measured 0).
__device__ __forceinline__ int lidx32(int r, int kb) {
    return r * 32 + ((kb ^ ((r >> 1) & 3)) << 3);
}

// Old 128B-row layout (fallback kernel only; r3/r5/r7 measured ~0 conflicts)
__device__ __forceinline__ int lidx(int r, int kb) {
    return r * 64 + ((kb ^ (r & 7)) << 3);
}

// --- Kernel 1b: X -> bf16 (RNE), gathered by sorted position, pre-swizzled.
// Key = expert-local position (r7-verified); m0 is a multiple of 128 so
// (local>>1)&3 == (LDS row>>1)&3.
__global__ void xsplit_kernel(const float* __restrict__ xs,
                              const int* __restrict__ sorted,
                              const int* __restrict__ offs,
                              const int* __restrict__ actions,
                              unsigned char* __restrict__ xws) {
    const int rm = blockIdx.x * 4 + (threadIdx.x >> 6);
    const int t = threadIdx.x & 63;         // k-tile index 0..63
    const int src = sorted[rm];
    const int e = actions[src];
    const int f = ((rm - offs[e]) >> 1) & 3;
    const float* s = xs + (size_t)src * DIN + t * 32;
    uint4 L[4];
#pragma unroll
    for (int j = 0; j < 4; ++j) {
        float4 a = *(const float4*)(s + 8 * j);
        float4 b = *(const float4*)(s + 8 * j + 4);
        L[j].x = rne2(a.x, a.y); L[j].y = rne2(a.z, a.w);
        L[j].z = rne2(b.x, b.y); L[j].w = rne2(b.z, b.w);
    }
    uint4* dst = (uint4*)(xws + (size_t)rm * 4096 + (size_t)t * 64);
#pragma unroll
    for (int b = 0; b < 4; ++b)
        dst[b] = L[b ^ f];
}

// --- Kernel 2: grouped GEMM, pure bf16. Exact r9 schedule; BN=64 doubles
// active blocks to 1024 (4/CU) -> work-limited occupancy 2x. ---
// grid = (n=32 fastest, e=16, m=32); block 256 (2x2 waves, wave tile 64x32)
__global__ __launch_bounds__(256, 4)
void gemm_kernel(const unsigned char* __restrict__ xws,
                 const float* __restrict__ W,
                 const float* __restrict__ bias,
                 const int* __restrict__ offs,
                 const int* __restrict__ sorted,
                 float* __restrict__ out) {
    __shared__ __align__(16) unsigned short Xs[2][BM * 32];  // 2 x 8 KB
    __shared__ __align__(16) unsigned short Wl[BN * 32];     // 4 KB

    const int e = blockIdx.y;
    const int start = offs[e];
    const int cnt = offs[e + 1] - start;
    const int m0 = blockIdx.z * BM;
    if (m0 >= cnt) return;
    const int n0 = blockIdx.x * BN;

    const int tid = threadIdx.x;
    const int lane = tid & 63;
    const int wave = tid >> 6;
    const int wm = wave >> 1, wn = wave & 1;
    const int g = lane >> 4, rl = lane & 15;

    // W staging role: row swr (0..63), 8-float chunk wkq (0..3).
    // Bank check (16-lane-phase model): 8-lane groups hit slot-classes
    // {4r+wkq^f(r)} = two full rows = 8 distinct -> conflict-free.
    const int swr = tid >> 2;
    const int wkq = tid & 3;
    const float* wsrc = W + ((size_t)e * DOUT + n0 + swr) * DIN + wkq * 8;

    // X gload sources (2 insts/wave, 16 rows each). Clamp keeps OOB rows
    // in-bounds of xws; their outputs are never written back.
    const unsigned char* xsrc_i[2];
#pragma unroll
    for (int i = 0; i < 2; ++i) {
        int rg = start + m0 + wave * 32 + i * 16 + (lane >> 2);
        if (rg > BATCH - 1) rg = BATCH - 1;
        xsrc_i[i] = xws + (size_t)rg * 4096 + (size_t)(lane & 3) * 16;
    }

#define STAGE_X(BUF, KT) do {                                                  \
    _Pragma("unroll")                                                          \
    for (int _i = 0; _i < 2; ++_i)                                             \
        __builtin_amdgcn_global_load_lds(                                      \
            (const __attribute__((address_space(1))) void*)(xsrc_i[_i] + (size_t)(KT) * 64), \
            (__attribute__((address_space(3))) void*)&Xs[BUF][(wave * 32 + _i * 16) * 32], \
            16, 0, 0);                                                         \
} while (0)

    f32x4 acc[4][2];
#pragma unroll
    for (int i = 0; i < 4; ++i)
#pragma unroll
        for (int j = 0; j < 2; ++j) acc[i][j] = (f32x4){0.f, 0.f, 0.f, 0.f};

    // ---- prologue: W(0)->pwA, W(1)->pwB, X(0) in flight ----
    float4 pwA[2], pwB[2];
    pwA[0] = *(const float4*)(wsrc + 0 * 32);
    pwA[1] = *(const float4*)(wsrc + 0 * 32 + 4);
    pwB[0] = *(const float4*)(wsrc + 1 * 32);
    pwB[1] = *(const float4*)(wsrc + 1 * 32 + 4);
    STAGE_X(0, 0);

    int kt = 0;

#define KSTEP(PW, CUR, NXT) do {                                               \
    { /* A: convert W(kt) (loaded 2 iters ago) + 1 ds_write */                 \
      uint4 u;                                                                 \
      u.x = rne2(PW[0].x, PW[0].y); u.y = rne2(PW[0].z, PW[0].w);              \
      u.z = rne2(PW[1].x, PW[1].y); u.w = rne2(PW[1].z, PW[1].w);              \
      *(uint4*)&Wl[lidx32(swr, wkq)] = u; }                                    \
    /* B: stage X(kt+1) into NXT (2 gload_lds) */                              \
    STAGE_X(NXT, (kt + 1) & (NKT - 1));                                        \
    { /* C: W(kt+2) loads into PW (consumed 2 iters later) */                  \
      int _k2 = (kt + 2) & (NKT - 1);                                          \
      PW[0] = *(const float4*)(wsrc + _k2 * 32);                               \
      PW[1] = *(const float4*)(wsrc + _k2 * 32 + 4); }                         \
    /* D: X(kt) landed (oldest 2 of 8 vm-ops) + W ds_writes visible */         \
    __builtin_amdgcn_sched_barrier(0);                                         \
    asm volatile("s_waitcnt vmcnt(6) lgkmcnt(0)" ::: "memory");                \
    __builtin_amdgcn_sched_barrier(0);                                         \
    __builtin_amdgcn_s_barrier();                                              \
    { /* E: fragment ds_reads */                                               \
      bf16x8 ah[4], bh[2];                                                     \
      _Pragma("unroll")                                                        \
      for (int mi = 0; mi < 4; ++mi)                                           \
          ah[mi] = *(const bf16x8*)&Xs[CUR][lidx32(wm * 64 + mi * 16 + rl, g)];\
      _Pragma("unroll")                                                        \
      for (int ni = 0; ni < 2; ++ni)                                           \
          bh[ni] = *(const bf16x8*)&Wl[lidx32(wn * 32 + ni * 16 + rl, g)];     \
      /* F: reads retired -> next ds_write safe after barrier */               \
      __builtin_amdgcn_sched_barrier(0);                                       \
      asm volatile("s_waitcnt lgkmcnt(0)" ::: "memory");                       \
      __builtin_amdgcn_sched_barrier(0);                                       \
      __builtin_amdgcn_s_barrier();                                            \
      /* G: 8 MFMA */                                                          \
      __builtin_amdgcn_s_setprio(1);                                           \
      _Pragma("unroll")                                                        \
      for (int mi = 0; mi < 4; ++mi)                                           \
          _Pragma("unroll")                                                    \
          for (int ni = 0; ni < 2; ++ni)                                       \
              acc[mi][ni] = __builtin_amdgcn_mfma_f32_16x16x32_bf16(ah[mi], bh[ni], acc[mi][ni], 0, 0, 0); \
      __builtin_amdgcn_s_setprio(0); }                                         \
    ++kt;                                                                      \
} while (0)

#pragma unroll 1
    for (int it = 0; it < NKT / 2; ++it) {
        KSTEP(pwA, 0, 1);
        KSTEP(pwB, 1, 0);
    }
#undef KSTEP
#undef STAGE_X

    // ---- epilogue: bias add + scatter rows (mapping verified r3..r9) ----
    float bv[2];
#pragma unroll
    for (int ni = 0; ni < 2; ++ni)
        bv[ni] = bias[(size_t)e * DOUT + n0 + wn * 32 + ni * 16 + rl];
#pragma unroll
    for (int mi = 0; mi < 4; ++mi) {
#pragma unroll
        for (int j = 0; j < 4; ++j) {
            int rm = m0 + wm * 64 + mi * 16 + g * 4 + j;
            if (rm < cnt) {
                int s = sorted[start + rm];
                float* orow = out + (size_t)s * DOUT + n0 + wn * 32 + rl;
#pragma unroll
                for (int ni = 0; ni < 2; ++ni)
                    orow[ni * 16] = acc[mi][ni][j] + bv[ni];
            }
        }
    }
}

// --- Fallback (round-5 proven 3-product kernel) if workspace too small ---
__device__ __forceinline__ void split_pair(float x0, float x1, unsigned& h, unsigned& l) {
    unsigned b0 = __float_as_uint(x0), b1 = __float_as_uint(x1);
    unsigned h0 = b0 & 0xFFFF0000u;
    unsigned h1 = b1 & 0xFFFF0000u;
    h = h1 | (b0 >> 16);
    unsigned l0 = __float_as_uint(x0 - __uint_as_float(h0));
    unsigned l1 = __float_as_uint(x1 - __uint_as_float(h1));
    l = (l1 & 0xFFFF0000u) | (l0 >> 16);
}
__device__ __forceinline__ void split_f4pair(float4 a, float4 b, uint4& h, uint4& l) {
    split_pair(a.x, a.y, h.x, l.x);
    split_pair(a.z, a.w, h.y, l.y);
    split_pair(b.x, b.y, h.z, l.z);
    split_pair(b.z, b.w, h.w, l.w);
}

__global__ __launch_bounds__(256, 3)
void gemm_fb(const float* __restrict__ xs,
             const float* __restrict__ W,
             const float* __restrict__ bias,
             const int* __restrict__ offs,
             const int* __restrict__ sorted,
             float* __restrict__ out) {
    __shared__ __align__(16) unsigned short Xs[128 * 64];
    __shared__ __align__(16) unsigned short Ws[64 * 64];

    const int e = blockIdx.y;
    const int start = offs[e];
    const int cnt = offs[e + 1] - start;
    const int m0 = blockIdx.z * 128;
    if (m0 >= cnt) return;
    const int n0 = blockIdx.x * 64;

    const int tid = threadIdx.x;
    const int lane = tid & 63;
    const int wave = tid >> 6;
    const int wm = wave >> 1, wn = wave & 1;
    const int srow = tid & 127, kq = tid >> 7;
    const int swr = tid >> 2, wkq = tid & 3;

    const int rm_s = m0 + srow;
    const int xrow = (rm_s < cnt) ? sorted[start + rm_s] : -1;
    const float* xsrc = xs + (size_t)(xrow < 0 ? 0 : xrow) * DIN + kq * 16;
    const float* wsrc = W + ((size_t)e * DOUT + n0 + swr) * DIN + wkq * 8;

    f32x4 acc[4][2];
#pragma unroll
    for (int i = 0; i < 4; ++i)
#pragma unroll
        for (int j = 0; j < 2; ++j) acc[i][j] = (f32x4){0.f, 0.f, 0.f, 0.f};

    float4 px[4], pw[2];
#pragma unroll
    for (int j = 0; j < 4; ++j)
        px[j] = (xrow >= 0) ? *(const float4*)(xsrc + j * 4) : make_float4(0.f, 0.f, 0.f, 0.f);
    pw[0] = *(const float4*)(wsrc);
    pw[1] = *(const float4*)(wsrc + 4);

    for (int k0 = 0; k0 < DIN; k0 += 32) {
        {
            uint4 xh0, xl0, xh1, xl1, wh, wl;
            split_f4pair(px[0], px[1], xh0, xl0);
            split_f4pair(px[2], px[3], xh1, xl1);
            split_f4pair(pw[0], pw[1], wh, wl);
            *(uint4*)&Xs[lidx(srow, 2 * kq)]         = xh0;
            *(uint4*)&Xs[lidx(srow, 2 * kq + 1)]     = xh1;
            *(uint4*)&Xs[lidx(srow, 4 + 2 * kq)]     = xl0;
            *(uint4*)&Xs[lidx(srow, 4 + 2 * kq + 1)] = xl1;
            *(uint4*)&Ws[lidx(swr, wkq)]             = wh;
            *(uint4*)&Ws[lidx(swr, 4 + wkq)]         = wl;
        }
        __syncthreads();
        {
            int kn = (k0 + 32 < DIN) ? (k0 + 32) : 0;
#pragma unroll
            for (int j = 0; j < 4; ++j)
                px[j] = (xrow >= 0) ? *(const float4*)(xsrc + kn + j * 4) : make_float4(0.f, 0.f, 0.f, 0.f);
            pw[0] = *(const float4*)(wsrc + kn);
            pw[1] = *(const float4*)(wsrc + kn + 4);
        }
        {
            const int gg = lane >> 4, rrl = lane & 15;
            bf16x8 ah[4], al[4], bh[2], bl[2];
#pragma unroll
            for (int mi = 0; mi < 4; ++mi) {
                int R = wm * 64 + mi * 16 + rrl;
                ah[mi] = *(const bf16x8*)&Xs[lidx(R, gg)];
                al[mi] = *(const bf16x8*)&Xs[lidx(R, 4 + gg)];
            }
#pragma unroll
            for (int ni = 0; ni < 2; ++ni) {
                int R = wn * 32 + ni * 16 + rrl;
                bh[ni] = *(const bf16x8*)&Ws[lidx(R, gg)];
                bl[ni] = *(const bf16x8*)&Ws[lidx(R, 4 + gg)];
            }
#pragma unroll
            for (int mi = 0; mi < 4; ++mi)
#pragma unroll
                for (int ni = 0; ni < 2; ++ni)
                    acc[mi][ni] = __builtin_amdgcn_mfma_f32_16x16x32_bf16(ah[mi], bh[ni], acc[mi][ni], 0, 0, 0);
#pragma unroll
            for (int mi = 0; mi < 4; ++mi)
#pragma unroll
                for (int ni = 0; ni < 2; ++ni)
                    acc[mi][ni] = __builtin_amdgcn_mfma_f32_16x16x32_bf16(ah[mi], bl[ni], acc[mi][ni], 0, 0, 0);
#pragma unroll
            for (int mi = 0; mi < 4; ++mi)
#pragma unroll
                for (int ni = 0; ni < 2; ++ni)
                    acc[mi][ni] = __builtin_amdgcn_mfma_f32_16x16x32_bf16(al[mi], bh[ni], acc[mi][ni], 0, 0, 0);
        }
        __syncthreads();
    }

    const int gg = lane >> 4, rrl = lane & 15;
    float bv[2];
#pragma unroll
    for (int ni = 0; ni < 2; ++ni)
        bv[ni] = bias[(size_t)e * DOUT + n0 + wn * 32 + ni * 16 + rrl];
#pragma unroll
    for (int mi = 0; mi < 4; ++mi) {
#pragma unroll
        for (int j = 0; j < 4; ++j) {
            int rm = m0 + wm * 64 + mi * 16 + gg * 4 + j;
            if (rm < cnt) {
                int s = sorted[start + rm];
                float* orow = out + (size_t)s * DOUT + n0 + wn * 32 + rrl;
#pragma unroll
                for (int ni = 0; ni < 2; ++ni)
                    orow[ni * 16] = acc[mi][ni][j] + bv[ni];
            }
        }
    }
}

extern "C" void kernel_launch(void* const* d_in, const int* in_sizes, int n_in,
                              void* d_out, int out_size, void* d_ws, size_t ws_size,
                              hipStream_t stream) {
    const float* xs      = (const float*)d_in[0];
    const float* mxs     = (const float*)d_in[1];
    const int*   actions = (const int*)d_in[2];
    const float* W       = (const float*)d_in[3];
    const float* b       = (const float*)d_in[4];
    float* out = (float*)d_out;

    int* ws_i   = (int*)d_ws;
    int* offs   = ws_i;         // NEXP+1
    int* sorted = ws_i + 32;    // BATCH

    sort_kernel<<<1, 1024, 0, stream>>>(actions, mxs,
                                        out + (size_t)BATCH * DOUT, offs, sorted);

    if (ws_size >= WS_X_OFF + WS_X_BYTES) {
        unsigned char* xws = (unsigned char*)d_ws + WS_X_OFF;
        xsplit_kernel<<<BATCH / 4, 256, 0, stream>>>(xs, sorted, offs, actions, xws);
        dim3 grid(DOUT / BN, NEXP, BATCH / BM);   // n fastest: dense active prefix
        gemm_kernel<<<grid, 256, 0, stream>>>(xws, W, b, offs, sorted, out);
    } else {
        dim3 grid(DOUT / 64, NEXP, BATCH / 128);
        gemm_fb<<<grid, 256, 0, stream>>>(xs, W, b, offs, sorted, out);
    }
}

// Round 12
// 163.617 us; speedup vs baseline: 12.1148x; 1.0490x over previous
//
#include <hip/hip_runtime.h>
#include <hip/hip_bf16.h>

#define BATCH 4096
#define NEXP  16
#define DIN   2048
#define DOUT  2048

#define BM 128
#define BN 64
#define NKT 64            // 64 k-tiles of 32 elements

#define WS_X_OFF   65536
#define PADROWS    4352   // 4096 + 16*16 worst-case padding
#define WS_X_BYTES ((size_t)PADROWS * 4096)

typedef __attribute__((ext_vector_type(4))) float f32x4;
typedef __attribute__((ext_vector_type(8))) short bf16x8;

// --- Kernel 1: bucket sample indices by expert; write mxs/actions tail ---
// Also computes poffs[e]: 16-aligned padded offsets (fragment groups must
// not cross expert boundaries -> pad each expert to a 16-row multiple).
__global__ void sort_kernel(const int* __restrict__ actions,
                            const float* __restrict__ mxs,
                            float* __restrict__ out_tail,
                            int* __restrict__ offs,     // [17]
                            int* __restrict__ poffs,    // [17]
                            int* __restrict__ sorted) {
    __shared__ int s_cnt[NEXP];
    __shared__ int s_cur[NEXP];
    const int tid = threadIdx.x;
    if (tid < NEXP) s_cnt[tid] = 0;
    __syncthreads();
    for (int i = tid; i < BATCH; i += blockDim.x) {
        int a = actions[i];
        atomicAdd(&s_cnt[a], 1);
        out_tail[i] = mxs[i];
        out_tail[BATCH + i] = (float)a;
    }
    __syncthreads();
    if (tid == 0) {
        int run = 0, prun = 0;
        for (int e = 0; e < NEXP; ++e) {
            offs[e] = run;  s_cur[e] = run;
            poffs[e] = prun;
            run += s_cnt[e];
            prun += (s_cnt[e] + 15) & ~15;
        }
        offs[NEXP] = run;
        poffs[NEXP] = prun;
    }
    __syncthreads();
    // Bucket order is atomics-dependent, but each sample's output is computed
    // independently with fixed k-order -> output bit-deterministic.
    for (int i = tid; i < BATCH; i += blockDim.x) {
        int e = actions[i];
        int pos = atomicAdd(&s_cur[e], 1);
        sorted[pos] = i;
    }
}

// fp32 pair -> packed bf16 (round-to-nearest-even): [bf16(x1) | bf16(x0)]
__device__ __forceinline__ unsigned rne2(float x0, float x1) {
    unsigned b0 = __float_as_uint(x0), b1 = __float_as_uint(x1);
    b0 = b0 + 0x7FFFu + ((b0 >> 16) & 1u);
    b1 = b1 + 0x7FFFu + ((b1 >> 16) & 1u);
    return (b1 & 0xFFFF0000u) | (b0 >> 16);
}

// W LDS layout (r10-verified 0-conflict): row r = 32 bf16, block kb 0..3,
// physical block = kb ^ ((r>>1)&3).
__device__ __forceinline__ int lidx32(int r, int kb) {
    return r * 32 + ((kb ^ ((r >> 1) & 3)) << 3);
}

// Old 128B-row layout (fallback kernel only)
__device__ __forceinline__ int lidx(int r, int kb) {
    return r * 64 + ((kb ^ (r & 7)) << 3);
}

// --- Kernel 1b: X -> bf16 fragments, A-fragment-major ---
// Group = 16 padded rows of one expert = 64 KB block:
//   addr = grp*65536 + kt*1024 + g*256 + slot*16
// GEMM lane l reads grpbase + kt*1024 + l*16 = (row=l&15, kblock=l>>4) -> its
// A-frag directly (one coalesced dwordx4 per 16-row group).
// grid: PADROWS/16 blocks; block 256: slot = t&15, ktq = t>>4 (4 kt each)
__global__ void xsplit_kernel(const float* __restrict__ xs,
                              const int* __restrict__ sorted,
                              const int* __restrict__ offs,
                              const int* __restrict__ poffs,
                              unsigned char* __restrict__ xws) {
    const int t = threadIdx.x;
    const int slot = t & 15;
    const int ktq = t >> 4;                 // 0..15, covers kt = ktq*4..+3
    const int p = blockIdx.x * 16 + slot;   // padded row index
    if (p >= poffs[NEXP]) return;
    int e = 0;
#pragma unroll
    for (int i = 1; i < NEXP; ++i)
        if (p >= poffs[i]) e = i;
    const int local = p - poffs[e];
    if (local >= offs[e + 1] - offs[e]) return;   // tail pad row
    const int src = sorted[offs[e] + local];
    const float* srow = xs + (size_t)src * DIN;
    unsigned char* gbase = xws + (size_t)blockIdx.x * 65536;
#pragma unroll
    for (int q = 0; q < 4; ++q) {
        const int kt = ktq * 4 + q;
        const float* s = srow + kt * 32;
        uint4 L[4];
#pragma unroll
        for (int j = 0; j < 4; ++j) {
            float4 a = *(const float4*)(s + 8 * j);
            float4 b = *(const float4*)(s + 8 * j + 4);
            L[j].x = rne2(a.x, a.y); L[j].y = rne2(a.z, a.w);
            L[j].z = rne2(b.x, b.y); L[j].w = rne2(b.z, b.w);
        }
        unsigned char* d = gbase + kt * 1024 + slot * 16;
#pragma unroll
        for (int g = 0; g < 4; ++g)
            *(uint4*)(d + g * 256) = L[g];
    }
}

// --- Kernel 2: grouped GEMM, pure bf16. X A-frags DIRECT from xws
// (no X LDS, no X barrier); W via double-buffered LDS, one raw barrier
// per iter (read-CUR-then-write-NXT; race-audited). Waves 4x1.
// grid = (n=32 fastest, e=16, m=32); block 256.
__global__ __launch_bounds__(256, 4)
void gemm_kernel(const unsigned char* __restrict__ xws,
                 const float* __restrict__ W,
                 const float* __restrict__ bias,
                 const int* __restrict__ offs,
                 const int* __restrict__ poffs,
                 const int* __restrict__ sorted,
                 float* __restrict__ out) {
    __shared__ __align__(16) unsigned short Wl[2][BN * 32];  // 2 x 4 KB

    const int e = blockIdx.y;
    const int start = offs[e];
    const int cnt = offs[e + 1] - start;
    const int m0 = blockIdx.z * BM;
    if (m0 >= cnt) return;
    const int n0 = blockIdx.x * BN;

    const int tid = threadIdx.x;
    const int lane = tid & 63;
    const int wave = tid >> 6;
    const int g = lane >> 4, rl = lane & 15;

    // W staging role (r10-verified pattern): row swr 0..63, 8-fp32 chunk wkq.
    const int swr = tid >> 2;
    const int wkq = tid & 3;
    const float* wsrc = W + ((size_t)e * DOUT + n0 + swr) * DIN + wkq * 8;

    // X fragment group bases: wave owns rows wave*32 + mi*16 (mi 0,1).
    // Clamp group to buffer (r11 OOB fix): clamped groups only contain
    // rows >= cnt, whose outputs the epilogue never writes.
    const unsigned char* xb[2];
#pragma unroll
    for (int mi = 0; mi < 2; ++mi) {
        int prow = poffs[e] + m0 + wave * 32 + mi * 16;
        if (prow > PADROWS - 16) prow = PADROWS - 16;
        xb[mi] = xws + ((size_t)prow >> 4) * 65536 + (size_t)lane * 16;
    }

    f32x4 acc[2][4];
#pragma unroll
    for (int i = 0; i < 2; ++i)
#pragma unroll
        for (int j = 0; j < 4; ++j) acc[i][j] = (f32x4){0.f, 0.f, 0.f, 0.f};

    // ---- prologue ----
    float4 pwA[2], pwB[2];
    pwA[0] = *(const float4*)(wsrc);            // W(0)
    pwA[1] = *(const float4*)(wsrc + 4);
    pwB[0] = *(const float4*)(wsrc + 32);       // W(1)
    pwB[1] = *(const float4*)(wsrc + 32 + 4);
    bf16x8 axA[2], axB[2];
#pragma unroll
    for (int mi = 0; mi < 2; ++mi)
        axA[mi] = *(const bf16x8*)(xb[mi]);     // X(0) frags
    {   // pre-loop: ds_write W(0) into buf 0
        uint4 u;
        u.x = rne2(pwA[0].x, pwA[0].y); u.y = rne2(pwA[0].z, pwA[0].w);
        u.z = rne2(pwA[1].x, pwA[1].y); u.w = rne2(pwA[1].z, pwA[1].w);
        *(uint4*)&Wl[0][lidx32(swr, wkq)] = u;
        // reload pwA with W(2) (pwB holds W(1))
        pwA[0] = *(const float4*)(wsrc + 2 * 32);
        pwA[1] = *(const float4*)(wsrc + 2 * 32 + 4);
    }

    int kt = 0;

    // Per iter: [lgkm0+barrier] -> read W frags (CUR) -> issue X(kt+1) frag
    // loads -> conv+write W(kt+1) (NXT) -> reload pw with W(kt+3) -> MFMA.
    // Single barrier; X/W global loads fly across it (compiler-managed waits).
#define KSTEP(AXC, AXN, PWU, PAR) do {                                         \
    __builtin_amdgcn_sched_barrier(0);                                         \
    asm volatile("s_waitcnt lgkmcnt(0)" ::: "memory");                         \
    __builtin_amdgcn_sched_barrier(0);                                         \
    __builtin_amdgcn_s_barrier();                                              \
    __builtin_amdgcn_sched_barrier(0);                                         \
    bf16x8 bh[4];                                                              \
    _Pragma("unroll")                                                          \
    for (int ni = 0; ni < 4; ++ni)                                             \
        bh[ni] = *(const bf16x8*)&Wl[PAR][lidx32(ni * 16 + rl, g)];            \
    { /* X(kt+1) frag loads -> AXN (wrap on last iter: harmless reload) */     \
      int _kn = (kt + 1) & (NKT - 1);                                          \
      _Pragma("unroll")                                                        \
      for (int mi = 0; mi < 2; ++mi)                                           \
          AXN[mi] = *(const bf16x8*)(xb[mi] + _kn * 1024); }                   \
    { /* conv + ds_write W(kt+1) into NXT buffer */                            \
      uint4 u;                                                                 \
      u.x = rne2(PWU[0].x, PWU[0].y); u.y = rne2(PWU[0].z, PWU[0].w);          \
      u.z = rne2(PWU[1].x, PWU[1].y); u.w = rne2(PWU[1].z, PWU[1].w);          \
      *(uint4*)&Wl[PAR ^ 1][lidx32(swr, wkq)] = u; }                           \
    { /* reload PWU with W(kt+3) */                                            \
      int _k3 = (kt + 3) & (NKT - 1);                                          \
      PWU[0] = *(const float4*)(wsrc + _k3 * 32);                              \
      PWU[1] = *(const float4*)(wsrc + _k3 * 32 + 4); }                        \
    __builtin_amdgcn_s_setprio(1);                                             \
    _Pragma("unroll")                                                          \
    for (int mi = 0; mi < 2; ++mi)                                             \
        _Pragma("unroll")                                                      \
        for (int ni = 0; ni < 4; ++ni)                                         \
            acc[mi][ni] = __builtin_amdgcn_mfma_f32_16x16x32_bf16(AXC[mi], bh[ni], acc[mi][ni], 0, 0, 0); \
    __builtin_amdgcn_s_setprio(0);                                             \
    ++kt;                                                                      \
} while (0)

#pragma unroll 1
    for (int it = 0; it < NKT / 2; ++it) {
        KSTEP(axA, axB, pwB, 0);   // even kt: X in axA, W buf 0; write W(kt+1) from pwB
        KSTEP(axB, axA, pwA, 1);   // odd  kt
    }
#undef KSTEP

    // ---- epilogue: bias add + scatter rows (4x1 wave layout) ----
    float bv[4];
#pragma unroll
    for (int ni = 0; ni < 4; ++ni)
        bv[ni] = bias[(size_t)e * DOUT + n0 + ni * 16 + rl];
#pragma unroll
    for (int mi = 0; mi < 2; ++mi) {
#pragma unroll
        for (int j = 0; j < 4; ++j) {
            int rm = m0 + wave * 32 + mi * 16 + g * 4 + j;
            if (rm < cnt) {
                int s = sorted[start + rm];
                float* orow = out + (size_t)s * DOUT + n0 + rl;
#pragma unroll
                for (int ni = 0; ni < 4; ++ni)
                    orow[ni * 16] = acc[mi][ni][j] + bv[ni];
            }
        }
    }
}

// --- Fallback (round-5 proven 3-product kernel) if workspace too small ---
__device__ __forceinline__ void split_pair(float x0, float x1, unsigned& h, unsigned& l) {
    unsigned b0 = __float_as_uint(x0), b1 = __float_as_uint(x1);
    unsigned h0 = b0 & 0xFFFF0000u;
    unsigned h1 = b1 & 0xFFFF0000u;
    h = h1 | (b0 >> 16);
    unsigned l0 = __float_as_uint(x0 - __uint_as_float(h0));
    unsigned l1 = __float_as_uint(x1 - __uint_as_float(h1));
    l = (l1 & 0xFFFF0000u) | (l0 >> 16);
}
__device__ __forceinline__ void split_f4pair(float4 a, float4 b, uint4& h, uint4& l) {
    split_pair(a.x, a.y, h.x, l.x);
    split_pair(a.z, a.w, h.y, l.y);
    split_pair(b.x, b.y, h.z, l.z);
    split_pair(b.z, b.w, h.w, l.w);
}

__global__ __launch_bounds__(256, 3)
void gemm_fb(const float* __restrict__ xs,
             const float* __restrict__ W,
             const float* __restrict__ bias,
             const int* __restrict__ offs,
             const int* __restrict__ sorted,
             float* __restrict__ out) {
    __shared__ __align__(16) unsigned short Xs[128 * 64];
    __shared__ __align__(16) unsigned short Ws[64 * 64];

    const int e = blockIdx.y;
    const int start = offs[e];
    const int cnt = offs[e + 1] - start;
    const int m0 = blockIdx.z * 128;
    if (m0 >= cnt) return;
    const int n0 = blockIdx.x * 64;

    const int tid = threadIdx.x;
    const int lane = tid & 63;
    const int wave = tid >> 6;
    const int wm = wave >> 1, wn = wave & 1;
    const int srow = tid & 127, kq = tid >> 7;
    const int swr = tid >> 2, wkq = tid & 3;

    const int rm_s = m0 + srow;
    const int xrow = (rm_s < cnt) ? sorted[start + rm_s] : -1;
    const float* xsrc = xs + (size_t)(xrow < 0 ? 0 : xrow) * DIN + kq * 16;
    const float* wsrc = W + ((size_t)e * DOUT + n0 + swr) * DIN + wkq * 8;

    f32x4 acc[4][2];
#pragma unroll
    for (int i = 0; i < 4; ++i)
#pragma unroll
        for (int j = 0; j < 2; ++j) acc[i][j] = (f32x4){0.f, 0.f, 0.f, 0.f};

    float4 px[4], pw[2];
#pragma unroll
    for (int j = 0; j < 4; ++j)
        px[j] = (xrow >= 0) ? *(const float4*)(xsrc + j * 4) : make_float4(0.f, 0.f, 0.f, 0.f);
    pw[0] = *(const float4*)(wsrc);
    pw[1] = *(const float4*)(wsrc + 4);

    for (int k0 = 0; k0 < DIN; k0 += 32) {
        {
            uint4 xh0, xl0, xh1, xl1, wh, wl;
            split_f4pair(px[0], px[1], xh0, xl0);
            split_f4pair(px[2], px[3], xh1, xl1);
            split_f4pair(pw[0], pw[1], wh, wl);
            *(uint4*)&Xs[lidx(srow, 2 * kq)]         = xh0;
            *(uint4*)&Xs[lidx(srow, 2 * kq + 1)]     = xh1;
            *(uint4*)&Xs[lidx(srow, 4 + 2 * kq)]     = xl0;
            *(uint4*)&Xs[lidx(srow, 4 + 2 * kq + 1)] = xl1;
            *(uint4*)&Ws[lidx(swr, wkq)]             = wh;
            *(uint4*)&Ws[lidx(swr, 4 + wkq)]         = wl;
        }
        __syncthreads();
        {
            int kn = (k0 + 32 < DIN) ? (k0 + 32) : 0;
#pragma unroll
            for (int j = 0; j < 4; ++j)
                px[j] = (xrow >= 0) ? *(const float4*)(xsrc + kn + j * 4) : make_float4(0.f, 0.f, 0.f, 0.f);
            pw[0] = *(const float4*)(wsrc + kn);
            pw[1] = *(const float4*)(wsrc + kn + 4);
        }
        {
            const int gg = lane >> 4, rrl = lane & 15;
            bf16x8 ah[4], al[4], bh[2], bl[2];
#pragma unroll
            for (int mi = 0; mi < 4; ++mi) {
                int R = wm * 64 + mi * 16 + rrl;
                ah[mi] = *(const bf16x8*)&Xs[lidx(R, gg)];
                al[mi] = *(const bf16x8*)&Xs[lidx(R, 4 + gg)];
            }
#pragma unroll
            for (int ni = 0; ni < 2; ++ni) {
                int R = wn * 32 + ni * 16 + rrl;
                bh[ni] = *(const bf16x8*)&Ws[lidx(R, gg)];
                bl[ni] = *(const bf16x8*)&Ws[lidx(R, 4 + gg)];
            }
#pragma unroll
            for (int mi = 0; mi < 4; ++mi)
#pragma unroll
                for (int ni = 0; ni < 2; ++ni)
                    acc[mi][ni] = __builtin_amdgcn_mfma_f32_16x16x32_bf16(ah[mi], bh[ni], acc[mi][ni], 0, 0, 0);
#pragma unroll
            for (int mi = 0; mi < 4; ++mi)
#pragma unroll
                for (int ni = 0; ni < 2; ++ni)
                    acc[mi][ni] = __builtin_amdgcn_mfma_f32_16x16x32_bf16(ah[mi], bl[ni], acc[mi][ni], 0, 0, 0);
#pragma unroll
            for (int mi = 0; mi < 4; ++mi)
#pragma unroll
                for (int ni = 0; ni < 2; ++ni)
                    acc[mi][ni] = __builtin_amdgcn_mfma_f32_16x16x32_bf16(al[mi], bh[ni], acc[mi][ni], 0, 0, 0);
        }
        __syncthreads();
    }

    const int gg = lane >> 4, rrl = lane & 15;
    float bv[2];
#pragma unroll
    for (int ni = 0; ni < 2; ++ni)
        bv[ni] = bias[(size_t)e * DOUT + n0 + wn * 32 + ni * 16 + rrl];
#pragma unroll
    for (int mi = 0; mi < 4; ++mi) {
#pragma unroll
        for (int j = 0; j < 4; ++j) {
            int rm = m0 + wm * 64 + mi * 16 + gg * 4 + j;
            if (rm < cnt) {
                int s = sorted[start + rm];
                float* orow = out + (size_t)s * DOUT + n0 + wn * 32 + rrl;
#pragma unroll
                for (int ni = 0; ni < 2; ++ni)
                    orow[ni * 16] = acc[mi][ni][j] + bv[ni];
            }
        }
    }
}

extern "C" void kernel_launch(void* const* d_in, const int* in_sizes, int n_in,
                              void* d_out, int out_size, void* d_ws, size_t ws_size,
                              hipStream_t stream) {
    const float* xs      = (const float*)d_in[0];
    const float* mxs     = (const float*)d_in[1];
    const int*   actions = (const int*)d_in[2];
    const float* W       = (const float*)d_in[3];
    const float* b       = (const float*)d_in[4];
    float* out = (float*)d_out;

    int* ws_i   = (int*)d_ws;
    int* offs   = ws_i;          // [17]
    int* poffs  = ws_i + 20;     // [17]
    int* sorted = ws_i + 64;     // [BATCH]

    sort_kernel<<<1, 1024, 0, stream>>>(actions, mxs,
                                        out + (size_t)BATCH * DOUT,
                                        offs, poffs, sorted);

    if (ws_size >= WS_X_OFF + WS_X_BYTES) {
        unsigned char* xws = (unsigned char*)d_ws + WS_X_OFF;
        xsplit_kernel<<<PADROWS / 16, 256, 0, stream>>>(xs, sorted, offs, poffs, xws);
        dim3 grid(DOUT / BN, NEXP, BATCH / BM);   // n fastest: dense active prefix
        gemm_kernel<<<grid, 256, 0, stream>>>(xws, W, b, offs, poffs, sorted, out);
    } else {
        dim3 grid(DOUT / 64, NEXP, BATCH / 128);
        gemm_fb<<<grid, 256, 0, stream>>>(xs, W, b, offs, sorted, out);
    }
}